// Round 5
// baseline (882.274 us; speedup 1.0000x reference)
//
#include <hip/hip_runtime.h>
#include <math.h>

// Problem constants (match reference)
#define D_IN 17
#define DH   32      // hidden dim = H*C
#define TDIM 32
#define TABK 4096    // time-encoding table resolution (nearest-neighbor)

#define NBSH 7                   // nodes per bucket = 128
#define NBKMAX 1024              // max buckets supported
#define TILE 16384               // edges per tile block (bcount / s1)
#define ACCS 35                  // LDS accumulator stride: 32 ch + 2 sums + pad

// LDS weight pack offsets (floats) for node_prep
#define WL_OFF 0        // 32*17
#define BL_OFF 544
#define WQ_OFF 576      // 32*32
#define BQ_OFF 1600
#define WK_OFF 1632
#define BK_OFF 2656
#define WV_OFF 2688
#define BV_OFF 3712
#define WS_OFF 3744
#define BS_OFF 4768
#define WTOT   4800

__device__ __forceinline__ unsigned int f2bf(float x) {
    unsigned int u = __float_as_uint(x);
    return (u + 0x7fffu + ((u >> 16) & 1u)) >> 16;   // RTNE, no NaN expected
}
__device__ __forceinline__ float bfl(unsigned int u) { return __uint_as_float(u << 16); }
__device__ __forceinline__ float bfh(unsigned int u) { return __uint_as_float(u & 0xffff0000u); }

// ---------------------------------------------------------------------------
// Kernel 1: h1 = relu(x@Wl.T+bl); q (f32), k/v packed bf16 (128B/row), skip f32
//           block 0 also zeroes bcnt.
// ---------------------------------------------------------------------------
__global__ __launch_bounds__(256) void node_prep(
    const float* __restrict__ x,
    const float* __restrict__ Wl, const float* __restrict__ bl,
    const float* __restrict__ Wq, const float* __restrict__ bq,
    const float* __restrict__ Wk, const float* __restrict__ bk,
    const float* __restrict__ Wv, const float* __restrict__ bv,
    const float* __restrict__ Ws, const float* __restrict__ bs,
    float* __restrict__ qn, unsigned short* __restrict__ kvn,
    float* __restrict__ skv, int* __restrict__ bcnt, int N)
{
    if (blockIdx.x == 0) {
        for (int i = threadIdx.x; i < NBKMAX; i += 256) bcnt[i] = 0;
    }

    __shared__ float w[WTOT];
    {
        const float* srcs[10] = {Wl, bl, Wq, bq, Wk, bk, Wv, bv, Ws, bs};
        const int   sizes[10] = {544, 32, 1024, 32, 1024, 32, 1024, 32, 1024, 32};
        int off = 0;
        for (int seg = 0; seg < 10; ++seg) {
            const float* p = srcs[seg];
            int sz = sizes[seg];
            for (int i = threadIdx.x; i < sz; i += blockDim.x) w[off + i] = p[i];
            off += sz;
        }
    }
    __syncthreads();

    int n = blockIdx.x * blockDim.x + threadIdx.x;
    if (n >= N) return;

    float xv[D_IN];
#pragma unroll
    for (int j = 0; j < D_IN; ++j) xv[j] = x[(size_t)n * D_IN + j];

    float h1[DH];
#pragma unroll
    for (int i = 0; i < DH; ++i) {
        float acc = w[BL_OFF + i];
#pragma unroll
        for (int j = 0; j < D_IN; ++j) acc += xv[j] * w[WL_OFF + i * D_IN + j];
        h1[i] = fmaxf(acc, 0.0f);
    }

    float outr[DH];

#define MATVEC(WO, BO)                                                       \
    {                                                                        \
        _Pragma("unroll")                                                    \
        for (int i = 0; i < DH; ++i) {                                       \
            float acc = w[(BO) + i];                                         \
            _Pragma("unroll")                                                \
            for (int c = 0; c < 8; ++c) {                                    \
                float4 wv = *(const float4*)&w[(WO) + i * DH + c * 4];       \
                acc += h1[c * 4 + 0] * wv.x + h1[c * 4 + 1] * wv.y           \
                     + h1[c * 4 + 2] * wv.z + h1[c * 4 + 3] * wv.w;          \
            }                                                                \
            outr[i] = acc;                                                   \
        }                                                                    \
    }

    // q -> f32
    MATVEC(WQ_OFF, BQ_OFF)
    {
        float4* dst4 = (float4*)(qn + (size_t)n * DH);
#pragma unroll
        for (int c = 0; c < 8; ++c) {
            float4 o; o.x = outr[c*4+0]; o.y = outr[c*4+1];
            o.z = outr[c*4+2]; o.w = outr[c*4+3];
            dst4[c] = o;
        }
    }

    // k -> bf16 packed words 0..15
    unsigned int kw[16], vw[16];
    MATVEC(WK_OFF, BK_OFF)
#pragma unroll
    for (int i = 0; i < 16; ++i)
        kw[i] = f2bf(outr[2*i]) | (f2bf(outr[2*i+1]) << 16);

    // v -> bf16 packed words 16..31
    MATVEC(WV_OFF, BV_OFF)
#pragma unroll
    for (int i = 0; i < 16; ++i)
        vw[i] = f2bf(outr[2*i]) | (f2bf(outr[2*i+1]) << 16);

    {
        uint4* row = (uint4*)(kvn + (size_t)n * 64);
#pragma unroll
        for (int c = 0; c < 4; ++c) {
            uint4 o; o.x = kw[c*4+0]; o.y = kw[c*4+1]; o.z = kw[c*4+2]; o.w = kw[c*4+3];
            row[c] = o;
        }
#pragma unroll
        for (int c = 0; c < 4; ++c) {
            uint4 o; o.x = vw[c*4+0]; o.y = vw[c*4+1]; o.z = vw[c*4+2]; o.w = vw[c*4+3];
            row[4 + c] = o;
        }
    }

    // skip -> f32
    MATVEC(WS_OFF, BS_OFF)
    {
        float4* dst4 = (float4*)(skv + (size_t)n * DH);
#pragma unroll
        for (int c = 0; c < 8; ++c) {
            float4 o; o.x = outr[c*4+0]; o.y = outr[c*4+1];
            o.z = outr[c*4+2]; o.w = outr[c*4+3];
            dst4[c] = o;
        }
    }
#undef MATVEC
}

// ---------------------------------------------------------------------------
// Kernel 2: time-encoding lookup table (nearest-neighbor, TABK+1 rows)
// ---------------------------------------------------------------------------
__global__ __launch_bounds__(64) void build_table(
    const float* __restrict__ We, const float* __restrict__ be,
    const float* __restrict__ freq, const float* __restrict__ phase,
    float* __restrict__ table)
{
    int k = blockIdx.x * blockDim.x + threadIdx.x;
    if (k > TABK) return;
    float r = -1.0f + 2.0f * (float)k / (float)TABK;
    float cj[TDIM];
#pragma unroll
    for (int j = 0; j < TDIM; ++j) cj[j] = cosf(r * freq[j] + phase[j]);
#pragma unroll 4
    for (int o = 0; o < DH; ++o) {
        float acc = be[o];
#pragma unroll
        for (int j = 0; j < TDIM; ++j) acc += cj[j] * We[o * TDIM + j];
        table[(size_t)k * DH + o] = acc;
    }
}

// ---------------------------------------------------------------------------
// bcount: coarse-bucket histogram (LDS-aggregated)
// ---------------------------------------------------------------------------
__global__ __launch_bounds__(256) void bcount_k(
    const int* __restrict__ ei, int* __restrict__ bcnt, int E, int NBK)
{
    __shared__ int lc[NBKMAX];
    for (int i = threadIdx.x; i < NBKMAX; i += 256) lc[i] = 0;
    __syncthreads();
    int base = blockIdx.x * TILE;
#pragma unroll 4
    for (int i = 0; i < TILE / 256; ++i) {
        int e = base + i * 256 + threadIdx.x;
        if (e < E) atomicAdd(&lc[((unsigned int)ei[E + e]) >> NBSH], 1);
    }
    __syncthreads();
    for (int b = threadIdx.x; b < NBK; b += 256) {
        int c = lc[b];
        if (c) atomicAdd(&bcnt[b], c);
    }
}

// ---------------------------------------------------------------------------
// bscan: single block; exclusive scan of bcnt -> bstart, init bcur
// ---------------------------------------------------------------------------
__global__ __launch_bounds__(1024) void bscan_k(
    const int* __restrict__ bcnt, int* __restrict__ bstart,
    int* __restrict__ bcur, int E, int NBK)
{
    __shared__ int sd[1024];
    int t = threadIdx.x;
    int v0 = (t < NBK) ? bcnt[t] : 0;
    sd[t] = v0;
    __syncthreads();
    for (int st = 1; st < 1024; st <<= 1) {
        int v = (t >= st) ? sd[t - st] : 0;
        __syncthreads();
        sd[t] += v;
        __syncthreads();
    }
    int ex = sd[t] - v0;
    if (t < NBK) { bstart[t] = ex; bcur[t] = ex; }
    if (t == 0)  { bstart[NBK] = E; }
}

// ---------------------------------------------------------------------------
// S1: bucketed staging scatter. stg entry = {src | localdst<<17, rel bits}
// ---------------------------------------------------------------------------
__global__ __launch_bounds__(256) void s1_bucket(
    const int* __restrict__ ei, const float* __restrict__ t,
    const float* __restrict__ ntime,
    int* __restrict__ bcur, int2* __restrict__ stg, int E, int NBK)
{
    __shared__ int lcnt[NBKMAX];
    __shared__ int lpos[NBKMAX];
    int base = blockIdx.x * TILE;
    for (int i = threadIdx.x; i < NBKMAX; i += 256) lcnt[i] = 0;
    __syncthreads();

    // phase A: per-bucket counts for this tile
#pragma unroll 4
    for (int i = 0; i < TILE / 256; ++i) {
        int e = base + i * 256 + threadIdx.x;
        if (e < E) atomicAdd(&lcnt[((unsigned int)ei[E + e]) >> NBSH], 1);
    }
    __syncthreads();

    // reserve global runs
    for (int b = threadIdx.x; b < NBK; b += 256) {
        int c = lcnt[b];
        lpos[b] = (c > 0) ? atomicAdd(&bcur[b], c) : 0;
    }
    __syncthreads();

    // phase B: write staged entries
#pragma unroll 4
    for (int i = 0; i < TILE / 256; ++i) {
        int e = base + i * 256 + threadIdx.x;
        if (e < E) {
            int d = ei[E + e];
            int s = ei[e];
            float rel = ntime[s] - t[e];
            int b = ((unsigned int)d) >> NBSH;
            int pos = atomicAdd(&lpos[b], 1);
            stg[pos] = make_int2(s | ((d & ((1 << NBSH) - 1)) << 17), __float_as_int(rel));
        }
    }
}

// ---------------------------------------------------------------------------
// fused_agg: one block per bucket (128 nodes). Edge-parallel with LDS float
// accumulators (atomic-free global); epilogue fused (divide/skip/out/logsm).
// ---------------------------------------------------------------------------
__global__ __launch_bounds__(256, 4) void fused_agg(
    const int* __restrict__ bstart, const int2* __restrict__ stg,
    const float* __restrict__ qn, const unsigned short* __restrict__ kvn,
    const float* __restrict__ skv, const float* __restrict__ table,
    const float* __restrict__ Wout, const float* __restrict__ bout,
    float* __restrict__ out, int N)
{
    __shared__ float lacc[(1 << NBSH) * ACCS];
    int t = threadIdx.x;
    for (int i = t; i < (1 << NBSH) * ACCS; i += 256) lacc[i] = 0.0f;
    __syncthreads();

    int nb0 = blockIdx.x << NBSH;
    int lo = bstart[blockIdx.x];
    int hi = bstart[blockIdx.x + 1];

    for (int i = lo + t; i < hi; i += 256) {
        int2 pl = stg[i];
        int ld  = ((unsigned int)pl.x) >> 17;
        int src = pl.x & 0x1FFFF;
        float rel = __int_as_float(pl.y);
        float u = fmaf(rel, (float)(TABK / 2), (float)(TABK / 2) + 0.5f);
        int i0 = (int)u;
        i0 = min(max(i0, 0), TABK);

        const float4* tr = (const float4*)(table + (size_t)i0 * DH);
        const uint2*  kv = (const uint2*)(kvn + (size_t)src * 64);
        const float4* qp = (const float4*)(qn + (size_t)(nb0 + ld) * DH);

        float4 tv[8];
#pragma unroll
        for (int c = 0; c < 8; ++c) tv[c] = tr[c];

        float a0 = 0.0f, a1 = 0.0f;
#pragma unroll
        for (int c = 0; c < 8; ++c) {
            float4 q4 = qp[c];
            uint2  kwv = kv[c];
            float p = q4.x * (bfl(kwv.x) + tv[c].x)
                    + q4.y * (bfh(kwv.x) + tv[c].y)
                    + q4.z * (bfl(kwv.y) + tv[c].z)
                    + q4.w * (bfh(kwv.y) + tv[c].w);
            if (c < 4) a0 += p; else a1 += p;
        }
        float w0 = __expf(a0 * 0.25f);   // 1/sqrt(C)=0.25; logits tiny, no max needed
        float w1 = __expf(a1 * 0.25f);

        float* ab = &lacc[ld * ACCS];
#pragma unroll
        for (int c = 0; c < 8; ++c) {
            uint2 vwv = kv[8 + c];
            float wgt = (c < 4) ? w0 : w1;
            atomicAdd(&ab[c * 4 + 0], (bfl(vwv.x) + tv[c].x) * wgt);
            atomicAdd(&ab[c * 4 + 1], (bfh(vwv.x) + tv[c].y) * wgt);
            atomicAdd(&ab[c * 4 + 2], (bfl(vwv.y) + tv[c].z) * wgt);
            atomicAdd(&ab[c * 4 + 3], (bfh(vwv.y) + tv[c].w) * wgt);
        }
        atomicAdd(&ab[32], w0);
        atomicAdd(&ab[33], w1);
    }
    __syncthreads();

    // epilogue: 8 threads per node, 32 nodes per pass, 4 passes
    int sub = t & 7;
    const float4 w0v = *(const float4*)(Wout + sub * 4);
    const float4 w1v = *(const float4*)(Wout + DH + sub * 4);
#pragma unroll
    for (int p = 0; p < (1 << NBSH) / 32; ++p) {
        int node = p * 32 + (t >> 3);
        int g = nb0 + node;
        if (g < N) {
            float* ab = &lacc[node * ACCS];
            float s0 = ab[32], s1 = ab[33];
            float r0 = (s0 > 0.0f) ? 1.0f / s0 : 0.0f;
            float r1 = (s1 > 0.0f) ? 1.0f / s1 : 0.0f;
            float r = (sub < 4) ? r0 : r1;
            float a0 = ab[sub * 4 + 0], a1 = ab[sub * 4 + 1];
            float a2 = ab[sub * 4 + 2], a3 = ab[sub * 4 + 3];
            const float4 sk = *(const float4*)(skv + (size_t)g * DH + sub * 4);
            float h0 = a0 * r + sk.x;
            float h1 = a1 * r + sk.y;
            float h2 = a2 * r + sk.z;
            float h3 = a3 * r + sk.w;

            float l0 = h0 * w0v.x + h1 * w0v.y + h2 * w0v.z + h3 * w0v.w;
            float l1 = h0 * w1v.x + h1 * w1v.y + h2 * w1v.z + h3 * w1v.w;
            l0 += __shfl_xor(l0, 1); l0 += __shfl_xor(l0, 2); l0 += __shfl_xor(l0, 4);
            l1 += __shfl_xor(l1, 1); l1 += __shfl_xor(l1, 2); l1 += __shfl_xor(l1, 4);

            if (sub == 0) {
                l0 += bout[0];
                l1 += bout[1];
                float m = fmaxf(l0, l1);
                float lse = m + logf(__expf(l0 - m) + __expf(l1 - m));
                float2 o; o.x = l0 - lse; o.y = l1 - lse;
                *(float2*)(out + (size_t)g * 2) = o;
            }
        }
    }
}

// ---------------------------------------------------------------------------
extern "C" void kernel_launch(void* const* d_in, const int* in_sizes, int n_in,
                              void* d_out, int out_size, void* d_ws, size_t ws_size,
                              hipStream_t stream)
{
    const float* x      = (const float*)d_in[0];
    const int*   ei     = (const int*)d_in[1];
    const float* t      = (const float*)d_in[2];
    const float* ntime  = (const float*)d_in[3];
    const float* freq   = (const float*)d_in[4];
    const float* phase  = (const float*)d_in[5];
    const float* Wl     = (const float*)d_in[6];
    const float* bl     = (const float*)d_in[7];
    const float* Wq     = (const float*)d_in[8];
    const float* bq     = (const float*)d_in[9];
    const float* Wk     = (const float*)d_in[10];
    const float* bk     = (const float*)d_in[11];
    const float* Wv     = (const float*)d_in[12];
    const float* bv     = (const float*)d_in[13];
    const float* We     = (const float*)d_in[14];
    const float* be     = (const float*)d_in[15];
    const float* Ws     = (const float*)d_in[16];
    const float* bs     = (const float*)d_in[17];
    const float* Wout   = (const float*)d_in[18];
    const float* bout   = (const float*)d_in[19];

    const int E = in_sizes[2];        // t has E elements
    const int N = in_sizes[3];        // node_time has N elements
    const int NBK = (N + (1 << NBSH) - 1) >> NBSH;   // buckets of 128 nodes

    char* wsb = (char*)d_ws;
    int2*  stg  = (int2*)wsb;               wsb += (size_t)E * sizeof(int2);
    float* qn   = (float*)wsb;              wsb += (size_t)N * DH * 4;
    unsigned short* kvn = (unsigned short*)wsb; wsb += (size_t)N * 64 * 2;
    float* skv  = (float*)wsb;              wsb += (size_t)N * DH * 4;
    float* tab  = (float*)wsb;              wsb += (size_t)(TABK + 1) * DH * 4;
    int*   bcnt = (int*)wsb;                wsb += NBKMAX * 4;
    int*   bstart = (int*)wsb;              wsb += (NBKMAX + 1) * 4;
    int*   bcur = (int*)wsb;                wsb += NBKMAX * 4;

    float* out = (float*)d_out;

    int nblk = (N + 255) / 256;
    int tblk = (E + TILE - 1) / TILE;

    node_prep<<<nblk, 256, 0, stream>>>(x, Wl, bl, Wq, bq, Wk, bk, Wv, bv, Ws, bs,
                                        qn, kvn, skv, bcnt, N);
    build_table<<<(TABK + 64) / 64, 64, 0, stream>>>(We, be, freq, phase, tab);
    bcount_k<<<tblk, 256, 0, stream>>>(ei, bcnt, E, NBK);
    bscan_k<<<1, 1024, 0, stream>>>(bcnt, bstart, bcur, E, NBK);
    s1_bucket<<<tblk, 256, 0, stream>>>(ei, t, ntime, bcur, stg, E, NBK);
    fused_agg<<<NBK, 256, 0, stream>>>(bstart, stg, qn, kvn, skv, tab,
                                       Wout, bout, out, N);
}

// Round 6
// 260.295 us; speedup vs baseline: 3.3895x; 3.3895x over previous
//
#include <hip/hip_runtime.h>
#include <math.h>

// Problem constants (match reference)
#define D_IN 17
#define DH   32      // hidden dim = H*C
#define TDIM 32
#define TABK 4096    // time-encoding table resolution (nearest-neighbor)

#define NBSH 8                   // nodes per bucket = 256
#define NBKMAX 512               // max buckets supported
#define TILE 8192                // edges per tile block (bcount / s1)

// LDS weight pack offsets (floats) for node_prep
#define WL_OFF 0        // 32*17
#define BL_OFF 544
#define WQ_OFF 576      // 32*32
#define BQ_OFF 1600
#define WK_OFF 1632
#define BK_OFF 2656
#define WV_OFF 2688
#define BV_OFF 3712
#define WS_OFF 3744
#define BS_OFF 4768
#define WTOT   4800

__device__ __forceinline__ unsigned int f2bf(float x) {
    unsigned int u = __float_as_uint(x);
    return (u + 0x7fffu + ((u >> 16) & 1u)) >> 16;   // RTNE, no NaN expected
}
__device__ __forceinline__ float bfl(unsigned int u) { return __uint_as_float(u << 16); }
__device__ __forceinline__ float bfh(unsigned int u) { return __uint_as_float(u & 0xffff0000u); }

// ---------------------------------------------------------------------------
// Kernel 1: h1 = relu(x@Wl.T+bl); q (f32), k/v packed bf16 (128B/row), skip f32
//           block 0 also zeroes bcnt.
// ---------------------------------------------------------------------------
__global__ __launch_bounds__(256) void node_prep(
    const float* __restrict__ x,
    const float* __restrict__ Wl, const float* __restrict__ bl,
    const float* __restrict__ Wq, const float* __restrict__ bq,
    const float* __restrict__ Wk, const float* __restrict__ bk,
    const float* __restrict__ Wv, const float* __restrict__ bv,
    const float* __restrict__ Ws, const float* __restrict__ bs,
    float* __restrict__ qn, unsigned short* __restrict__ kvn,
    float* __restrict__ skv, int* __restrict__ bcnt, int N)
{
    if (blockIdx.x == 0) {
        for (int i = threadIdx.x; i < NBKMAX; i += 256) bcnt[i] = 0;
    }

    __shared__ float w[WTOT];
    {
        const float* srcs[10] = {Wl, bl, Wq, bq, Wk, bk, Wv, bv, Ws, bs};
        const int   sizes[10] = {544, 32, 1024, 32, 1024, 32, 1024, 32, 1024, 32};
        int off = 0;
        for (int seg = 0; seg < 10; ++seg) {
            const float* p = srcs[seg];
            int sz = sizes[seg];
            for (int i = threadIdx.x; i < sz; i += blockDim.x) w[off + i] = p[i];
            off += sz;
        }
    }
    __syncthreads();

    int n = blockIdx.x * blockDim.x + threadIdx.x;
    if (n >= N) return;

    float xv[D_IN];
#pragma unroll
    for (int j = 0; j < D_IN; ++j) xv[j] = x[(size_t)n * D_IN + j];

    float h1[DH];
#pragma unroll
    for (int i = 0; i < DH; ++i) {
        float acc = w[BL_OFF + i];
#pragma unroll
        for (int j = 0; j < D_IN; ++j) acc += xv[j] * w[WL_OFF + i * D_IN + j];
        h1[i] = fmaxf(acc, 0.0f);
    }

    float outr[DH];

#define MATVEC(WO, BO)                                                       \
    {                                                                        \
        _Pragma("unroll")                                                    \
        for (int i = 0; i < DH; ++i) {                                       \
            float acc = w[(BO) + i];                                         \
            _Pragma("unroll")                                                \
            for (int c = 0; c < 8; ++c) {                                    \
                float4 wv = *(const float4*)&w[(WO) + i * DH + c * 4];       \
                acc += h1[c * 4 + 0] * wv.x + h1[c * 4 + 1] * wv.y           \
                     + h1[c * 4 + 2] * wv.z + h1[c * 4 + 3] * wv.w;          \
            }                                                                \
            outr[i] = acc;                                                   \
        }                                                                    \
    }

    // q -> f32
    MATVEC(WQ_OFF, BQ_OFF)
    {
        float4* dst4 = (float4*)(qn + (size_t)n * DH);
#pragma unroll
        for (int c = 0; c < 8; ++c) {
            float4 o; o.x = outr[c*4+0]; o.y = outr[c*4+1];
            o.z = outr[c*4+2]; o.w = outr[c*4+3];
            dst4[c] = o;
        }
    }

    // k -> bf16 packed words 0..15
    unsigned int kw[16], vw[16];
    MATVEC(WK_OFF, BK_OFF)
#pragma unroll
    for (int i = 0; i < 16; ++i)
        kw[i] = f2bf(outr[2*i]) | (f2bf(outr[2*i+1]) << 16);

    // v -> bf16 packed words 16..31
    MATVEC(WV_OFF, BV_OFF)
#pragma unroll
    for (int i = 0; i < 16; ++i)
        vw[i] = f2bf(outr[2*i]) | (f2bf(outr[2*i+1]) << 16);

    {
        uint4* row = (uint4*)(kvn + (size_t)n * 64);
#pragma unroll
        for (int c = 0; c < 4; ++c) {
            uint4 o; o.x = kw[c*4+0]; o.y = kw[c*4+1]; o.z = kw[c*4+2]; o.w = kw[c*4+3];
            row[c] = o;
        }
#pragma unroll
        for (int c = 0; c < 4; ++c) {
            uint4 o; o.x = vw[c*4+0]; o.y = vw[c*4+1]; o.z = vw[c*4+2]; o.w = vw[c*4+3];
            row[4 + c] = o;
        }
    }

    // skip -> f32
    MATVEC(WS_OFF, BS_OFF)
    {
        float4* dst4 = (float4*)(skv + (size_t)n * DH);
#pragma unroll
        for (int c = 0; c < 8; ++c) {
            float4 o; o.x = outr[c*4+0]; o.y = outr[c*4+1];
            o.z = outr[c*4+2]; o.w = outr[c*4+3];
            dst4[c] = o;
        }
    }
#undef MATVEC
}

// ---------------------------------------------------------------------------
// Kernel 2: time-encoding lookup table (TABK+1 rows, nearest-neighbor use)
// ---------------------------------------------------------------------------
__global__ __launch_bounds__(64) void build_table(
    const float* __restrict__ We, const float* __restrict__ be,
    const float* __restrict__ freq, const float* __restrict__ phase,
    float* __restrict__ table)
{
    int k = blockIdx.x * blockDim.x + threadIdx.x;
    if (k > TABK) return;
    float r = -1.0f + 2.0f * (float)k / (float)TABK;
    float cj[TDIM];
#pragma unroll
    for (int j = 0; j < TDIM; ++j) cj[j] = cosf(r * freq[j] + phase[j]);
#pragma unroll 4
    for (int o = 0; o < DH; ++o) {
        float acc = be[o];
#pragma unroll
        for (int j = 0; j < TDIM; ++j) acc += cj[j] * We[o * TDIM + j];
        table[(size_t)k * DH + o] = acc;
    }
}

// ---------------------------------------------------------------------------
// bcount: coarse-bucket histogram (LDS-aggregated)
// ---------------------------------------------------------------------------
__global__ __launch_bounds__(256) void bcount_k(
    const int* __restrict__ ei, int* __restrict__ bcnt, int E, int NBK)
{
    __shared__ int lc[NBKMAX];
    for (int i = threadIdx.x; i < NBKMAX; i += 256) lc[i] = 0;
    __syncthreads();
    int base = blockIdx.x * TILE;
#pragma unroll 4
    for (int i = 0; i < TILE / 256; ++i) {
        int e = base + i * 256 + threadIdx.x;
        if (e < E) atomicAdd(&lc[((unsigned int)ei[E + e]) >> NBSH], 1);
    }
    __syncthreads();
    for (int b = threadIdx.x; b < NBK; b += 256) {
        int c = lc[b];
        if (c) atomicAdd(&bcnt[b], c);
    }
}

// ---------------------------------------------------------------------------
// bscan: single block; exclusive scan of bcnt -> bstart, init bcur, off[N]=E
// ---------------------------------------------------------------------------
__global__ __launch_bounds__(512) void bscan_k(
    const int* __restrict__ bcnt, int* __restrict__ bstart,
    int* __restrict__ bcur, int* __restrict__ off, int N, int E, int NBK)
{
    __shared__ int sd[512];
    int t = threadIdx.x;
    int v0 = (t < NBK) ? bcnt[t] : 0;
    sd[t] = v0;
    __syncthreads();
    for (int st = 1; st < 512; st <<= 1) {
        int v = (t >= st) ? sd[t - st] : 0;
        __syncthreads();
        sd[t] += v;
        __syncthreads();
    }
    int ex = sd[t] - v0;
    if (t < NBK) { bstart[t] = ex; bcur[t] = ex; }
    if (t == 0)  { bstart[NBK] = E; off[N] = E; }   // off[N] fix (round-4 bug)
}

// ---------------------------------------------------------------------------
// S1: bucketed staging scatter. stg = {src | localdst<<17, tabidx}
// ---------------------------------------------------------------------------
__global__ __launch_bounds__(256) void s1_bucket(
    const int* __restrict__ ei, const float* __restrict__ t,
    const float* __restrict__ ntime,
    int* __restrict__ bcur, int2* __restrict__ stg, int E, int NBK)
{
    __shared__ int lcnt[NBKMAX];
    __shared__ int lpos[NBKMAX];
    int base = blockIdx.x * TILE;
    for (int i = threadIdx.x; i < NBKMAX; i += 256) lcnt[i] = 0;
    __syncthreads();

    // phase A: per-bucket counts for this tile
#pragma unroll 4
    for (int i = 0; i < TILE / 256; ++i) {
        int e = base + i * 256 + threadIdx.x;
        if (e < E) atomicAdd(&lcnt[((unsigned int)ei[E + e]) >> NBSH], 1);
    }
    __syncthreads();

    // reserve global runs
    for (int b = threadIdx.x; b < NBK; b += 256) {
        int c = lcnt[b];
        lpos[b] = (c > 0) ? atomicAdd(&bcur[b], c) : 0;
    }
    __syncthreads();

    // phase B: write staged entries (tab index precomputed here)
#pragma unroll 4
    for (int i = 0; i < TILE / 256; ++i) {
        int e = base + i * 256 + threadIdx.x;
        if (e < E) {
            int d = ei[E + e];
            int s = ei[e];
            float rel = ntime[s] - t[e];
            float u = fmaf(rel, (float)(TABK / 2), (float)(TABK / 2) + 0.5f);
            int idx = (int)u;
            idx = min(max(idx, 0), TABK - 1);
            int b = ((unsigned int)d) >> NBSH;
            int pos = atomicAdd(&lpos[b], 1);
            stg[pos] = make_int2(s | ((d & ((1 << NBSH) - 1)) << 17), idx);
        }
    }
}

// ---------------------------------------------------------------------------
// S2: per-bucket LDS histogram + scan -> off[]; scatter 4B payload
//     payload = src | tabidx<<17
// ---------------------------------------------------------------------------
__global__ __launch_bounds__(256) void s2_hist_scatter(
    const int* __restrict__ bstart, const int2* __restrict__ stg,
    int* __restrict__ payload, int* __restrict__ off, int N)
{
    __shared__ int lcnt[1 << NBSH];
    int t = threadIdx.x;
    int nb0 = blockIdx.x << NBSH;
    lcnt[t] = 0;
    __syncthreads();

    int lo = bstart[blockIdx.x];
    int hi = bstart[blockIdx.x + 1];

    // pass 1: local histogram
    for (int i = lo + t; i < hi; i += 256)
        atomicAdd(&lcnt[((unsigned int)stg[i].x) >> 17], 1);
    __syncthreads();

    // in-place Hillis-Steele inclusive scan (256 wide)
    int cntv = lcnt[t];
    for (int st = 1; st < 256; st <<= 1) {
        int v = (t >= st) ? lcnt[t - st] : 0;
        __syncthreads();
        lcnt[t] += v;
        __syncthreads();
    }
    int gpos = lo + lcnt[t] - cntv;   // global CSR offset for node nb0+t
    if (nb0 + t < N) off[nb0 + t] = gpos;
    __syncthreads();
    lcnt[t] = gpos;                    // becomes the scatter cursor
    __syncthreads();

    // pass 2: scatter to final position (stg run is L2-hot)
    for (int i = lo + t; i < hi; i += 256) {
        int2 pl = stg[i];
        int ld = ((unsigned int)pl.x) >> 17;
        int pos = atomicAdd(&lcnt[ld], 1);
        payload[pos] = (pl.x & 0x1FFFF) | (pl.y << 17);
    }
}

// ---------------------------------------------------------------------------
// gather + finalize. 16 lanes per dst (2 edges in flight), no atomics.
// ---------------------------------------------------------------------------
__global__ __launch_bounds__(256) void gather_pass(
    const int* __restrict__ off, const int* __restrict__ payload,
    const float* __restrict__ qn, const unsigned short* __restrict__ kvn,
    const float* __restrict__ skv, const float* __restrict__ table,
    const float* __restrict__ Wout, const float* __restrict__ bout,
    float* __restrict__ out, int N)
{
    int tid = blockIdx.x * blockDim.x + threadIdx.x;
    int d    = tid >> 4;         // 16 lanes per dst
    int half = (tid >> 3) & 1;   // edge parity
    int sub  = tid & 7;          // channel group: 4 floats each
    if (d >= N) return;

    const float4 q = *(const float4*)(qn + (size_t)d * DH + sub * 4);
    float4 acc; acc.x = acc.y = acc.z = acc.w = 0.0f;
    float ssum = 0.0f;

    int beg = off[d];
    int end = off[d + 1];
    for (int j = beg + half; j < end; j += 2) {
        int p = payload[j];
        int src = p & 0x1FFFF;
        int idx = ((unsigned int)p) >> 17;

        const float4 ev = *(const float4*)(table + (size_t)idx * DH + sub * 4);
        const unsigned short* row = kvn + (size_t)src * 64;
        uint2 kb = *(const uint2*)(row + sub * 4);
        uint2 vb = *(const uint2*)(row + 32 + sub * 4);

        float part = q.x * (bfl(kb.x) + ev.x) + q.y * (bfh(kb.x) + ev.y)
                   + q.z * (bfl(kb.y) + ev.z) + q.w * (bfh(kb.y) + ev.w);
        part += __shfl_xor(part, 1);
        part += __shfl_xor(part, 2);
        float wgt = __expf(part * 0.25f);   // 1/sqrt(C)=0.25; logits tiny, no max needed
        ssum += wgt;

        acc.x += (bfl(vb.x) + ev.x) * wgt;
        acc.y += (bfh(vb.x) + ev.y) * wgt;
        acc.z += (bfl(vb.y) + ev.z) * wgt;
        acc.w += (bfh(vb.y) + ev.w) * wgt;
    }

    // combine the two edge-parity halves
    acc.x += __shfl_xor(acc.x, 8);
    acc.y += __shfl_xor(acc.y, 8);
    acc.z += __shfl_xor(acc.z, 8);
    acc.w += __shfl_xor(acc.w, 8);
    ssum  += __shfl_xor(ssum, 8);

    float r = (ssum > 0.0f) ? 1.0f / ssum : 0.0f;
    const float4 sk = *(const float4*)(skv + (size_t)d * DH + sub * 4);
    float h0 = acc.x * r + sk.x;
    float h1 = acc.y * r + sk.y;
    float h2 = acc.z * r + sk.z;
    float h3 = acc.w * r + sk.w;

    const float4 w0 = *(const float4*)(Wout + sub * 4);
    const float4 w1 = *(const float4*)(Wout + DH + sub * 4);
    float l0 = h0 * w0.x + h1 * w0.y + h2 * w0.z + h3 * w0.w;
    float l1 = h0 * w1.x + h1 * w1.y + h2 * w1.z + h3 * w1.w;
    l0 += __shfl_xor(l0, 1); l0 += __shfl_xor(l0, 2); l0 += __shfl_xor(l0, 4);
    l1 += __shfl_xor(l1, 1); l1 += __shfl_xor(l1, 2); l1 += __shfl_xor(l1, 4);

    if ((tid & 15) == 0) {
        l0 += bout[0];
        l1 += bout[1];
        float m = fmaxf(l0, l1);
        float lse = m + logf(__expf(l0 - m) + __expf(l1 - m));
        float2 o; o.x = l0 - lse; o.y = l1 - lse;
        *(float2*)(out + (size_t)d * 2) = o;
    }
}

// ---------------------------------------------------------------------------
extern "C" void kernel_launch(void* const* d_in, const int* in_sizes, int n_in,
                              void* d_out, int out_size, void* d_ws, size_t ws_size,
                              hipStream_t stream)
{
    const float* x      = (const float*)d_in[0];
    const int*   ei     = (const int*)d_in[1];
    const float* t      = (const float*)d_in[2];
    const float* ntime  = (const float*)d_in[3];
    const float* freq   = (const float*)d_in[4];
    const float* phase  = (const float*)d_in[5];
    const float* Wl     = (const float*)d_in[6];
    const float* bl     = (const float*)d_in[7];
    const float* Wq     = (const float*)d_in[8];
    const float* bq     = (const float*)d_in[9];
    const float* Wk     = (const float*)d_in[10];
    const float* bk     = (const float*)d_in[11];
    const float* Wv     = (const float*)d_in[12];
    const float* bv     = (const float*)d_in[13];
    const float* We     = (const float*)d_in[14];
    const float* be     = (const float*)d_in[15];
    const float* Ws     = (const float*)d_in[16];
    const float* bs     = (const float*)d_in[17];
    const float* Wout   = (const float*)d_in[18];
    const float* bout   = (const float*)d_in[19];

    const int E = in_sizes[2];        // t has E elements
    const int N = in_sizes[3];        // node_time has N elements
    const int NBK = (N + (1 << NBSH) - 1) >> NBSH;   // buckets of 256 nodes

    char* wsb = (char*)d_ws;
    int2*  stg     = (int2*)wsb;            wsb += (size_t)E * sizeof(int2);
    int*   payload = (int*)wsb;             wsb += (size_t)E * sizeof(int);
    float* qn   = (float*)wsb;              wsb += (size_t)N * DH * 4;
    unsigned short* kvn = (unsigned short*)wsb; wsb += (size_t)N * 64 * 2;
    float* skv  = (float*)wsb;              wsb += (size_t)N * DH * 4;
    float* tab  = (float*)wsb;              wsb += (size_t)(TABK + 1) * DH * 4;
    int*   off  = (int*)wsb;                wsb += (size_t)(N + 1) * 4;
    int*   bcnt = (int*)wsb;                wsb += NBKMAX * 4;
    int*   bstart = (int*)wsb;              wsb += (NBKMAX + 1) * 4;
    int*   bcur = (int*)wsb;                wsb += NBKMAX * 4;

    float* out = (float*)d_out;

    int nblk = (N + 255) / 256;
    int tblk = (E + TILE - 1) / TILE;

    node_prep<<<nblk, 256, 0, stream>>>(x, Wl, bl, Wq, bq, Wk, bk, Wv, bv, Ws, bs,
                                        qn, kvn, skv, bcnt, N);
    build_table<<<(TABK + 64) / 64, 64, 0, stream>>>(We, be, freq, phase, tab);
    bcount_k<<<tblk, 256, 0, stream>>>(ei, bcnt, E, NBK);
    bscan_k<<<1, 512, 0, stream>>>(bcnt, bstart, bcur, off, N, E, NBK);
    s1_bucket<<<tblk, 256, 0, stream>>>(ei, t, ntime, bcur, stg, E, NBK);
    s2_hist_scatter<<<NBK, 256, 0, stream>>>(bstart, stg, payload, off, N);

    int gblk = ((size_t)N * 16 + 255) / 256;
    gather_pass<<<gblk, 256, 0, stream>>>(off, payload, qn, kvn, skv,
                                          tab, Wout, bout, out, N);
}

// Round 7
// 227.451 us; speedup vs baseline: 3.8790x; 1.1444x over previous
//
#include <hip/hip_runtime.h>
#include <math.h>

// Problem constants (match reference)
#define D_IN 17
#define DH   32      // hidden dim = H*C
#define TDIM 32
#define TABK 4096    // time-encoding table resolution (nearest-neighbor)

#define NBSH 8                   // nodes per bucket = 256
#define NBKMAX 512               // max buckets supported
#define TILE 8192                // edges per tile block (bcount / s1)

// LDS weight pack offsets (floats) for node_prep
#define WL_OFF 0        // 32*17
#define BL_OFF 544
#define WQ_OFF 576      // 32*32
#define BQ_OFF 1600
#define WK_OFF 1632
#define BK_OFF 2656
#define WV_OFF 2688
#define BV_OFF 3712
#define WS_OFF 3744
#define BS_OFF 4768
#define WTOT   4800

__device__ __forceinline__ unsigned int f2bf(float x) {
    unsigned int u = __float_as_uint(x);
    return (u + 0x7fffu + ((u >> 16) & 1u)) >> 16;   // RTNE, no NaN expected
}
__device__ __forceinline__ float bfl(unsigned int u) { return __uint_as_float(u << 16); }
__device__ __forceinline__ float bfh(unsigned int u) { return __uint_as_float(u & 0xffff0000u); }

// ---------------------------------------------------------------------------
// Kernel 1: h1 = relu(x@Wl.T+bl); q (f32), k/v packed bf16 (128B/row), skip f32
//           block 0 also zeroes bcnt.
// ---------------------------------------------------------------------------
__global__ __launch_bounds__(256) void node_prep(
    const float* __restrict__ x,
    const float* __restrict__ Wl, const float* __restrict__ bl,
    const float* __restrict__ Wq, const float* __restrict__ bq,
    const float* __restrict__ Wk, const float* __restrict__ bk,
    const float* __restrict__ Wv, const float* __restrict__ bv,
    const float* __restrict__ Ws, const float* __restrict__ bs,
    float* __restrict__ qn, unsigned short* __restrict__ kvn,
    float* __restrict__ skv, int* __restrict__ bcnt, int N)
{
    if (blockIdx.x == 0) {
        for (int i = threadIdx.x; i < NBKMAX; i += 256) bcnt[i] = 0;
    }

    __shared__ float w[WTOT];
    {
        const float* srcs[10] = {Wl, bl, Wq, bq, Wk, bk, Wv, bv, Ws, bs};
        const int   sizes[10] = {544, 32, 1024, 32, 1024, 32, 1024, 32, 1024, 32};
        int off = 0;
        for (int seg = 0; seg < 10; ++seg) {
            const float* p = srcs[seg];
            int sz = sizes[seg];
            for (int i = threadIdx.x; i < sz; i += blockDim.x) w[off + i] = p[i];
            off += sz;
        }
    }
    __syncthreads();

    int n = blockIdx.x * blockDim.x + threadIdx.x;
    if (n >= N) return;

    float xv[D_IN];
#pragma unroll
    for (int j = 0; j < D_IN; ++j) xv[j] = x[(size_t)n * D_IN + j];

    float h1[DH];
#pragma unroll
    for (int i = 0; i < DH; ++i) {
        float acc = w[BL_OFF + i];
#pragma unroll
        for (int j = 0; j < D_IN; ++j) acc += xv[j] * w[WL_OFF + i * D_IN + j];
        h1[i] = fmaxf(acc, 0.0f);
    }

    float outr[DH];

#define MATVEC(WO, BO)                                                       \
    {                                                                        \
        _Pragma("unroll")                                                    \
        for (int i = 0; i < DH; ++i) {                                       \
            float acc = w[(BO) + i];                                         \
            _Pragma("unroll")                                                \
            for (int c = 0; c < 8; ++c) {                                    \
                float4 wv = *(const float4*)&w[(WO) + i * DH + c * 4];       \
                acc += h1[c * 4 + 0] * wv.x + h1[c * 4 + 1] * wv.y           \
                     + h1[c * 4 + 2] * wv.z + h1[c * 4 + 3] * wv.w;          \
            }                                                                \
            outr[i] = acc;                                                   \
        }                                                                    \
    }

    // q -> f32
    MATVEC(WQ_OFF, BQ_OFF)
    {
        float4* dst4 = (float4*)(qn + (size_t)n * DH);
#pragma unroll
        for (int c = 0; c < 8; ++c) {
            float4 o; o.x = outr[c*4+0]; o.y = outr[c*4+1];
            o.z = outr[c*4+2]; o.w = outr[c*4+3];
            dst4[c] = o;
        }
    }

    // k -> bf16 packed words 0..15
    unsigned int kw[16], vw[16];
    MATVEC(WK_OFF, BK_OFF)
#pragma unroll
    for (int i = 0; i < 16; ++i)
        kw[i] = f2bf(outr[2*i]) | (f2bf(outr[2*i+1]) << 16);

    // v -> bf16 packed words 16..31
    MATVEC(WV_OFF, BV_OFF)
#pragma unroll
    for (int i = 0; i < 16; ++i)
        vw[i] = f2bf(outr[2*i]) | (f2bf(outr[2*i+1]) << 16);

    {
        uint4* row = (uint4*)(kvn + (size_t)n * 64);
#pragma unroll
        for (int c = 0; c < 4; ++c) {
            uint4 o; o.x = kw[c*4+0]; o.y = kw[c*4+1]; o.z = kw[c*4+2]; o.w = kw[c*4+3];
            row[c] = o;
        }
#pragma unroll
        for (int c = 0; c < 4; ++c) {
            uint4 o; o.x = vw[c*4+0]; o.y = vw[c*4+1]; o.z = vw[c*4+2]; o.w = vw[c*4+3];
            row[4 + c] = o;
        }
    }

    // skip -> f32
    MATVEC(WS_OFF, BS_OFF)
    {
        float4* dst4 = (float4*)(skv + (size_t)n * DH);
#pragma unroll
        for (int c = 0; c < 8; ++c) {
            float4 o; o.x = outr[c*4+0]; o.y = outr[c*4+1];
            o.z = outr[c*4+2]; o.w = outr[c*4+3];
            dst4[c] = o;
        }
    }
#undef MATVEC
}

// ---------------------------------------------------------------------------
// Kernel 2: time-encoding lookup table (TABK+1 rows, nearest-neighbor use)
// ---------------------------------------------------------------------------
__global__ __launch_bounds__(64) void build_table(
    const float* __restrict__ We, const float* __restrict__ be,
    const float* __restrict__ freq, const float* __restrict__ phase,
    float* __restrict__ table)
{
    int k = blockIdx.x * blockDim.x + threadIdx.x;
    if (k > TABK) return;
    float r = -1.0f + 2.0f * (float)k / (float)TABK;
    float cj[TDIM];
#pragma unroll
    for (int j = 0; j < TDIM; ++j) cj[j] = cosf(r * freq[j] + phase[j]);
#pragma unroll 4
    for (int o = 0; o < DH; ++o) {
        float acc = be[o];
#pragma unroll
        for (int j = 0; j < TDIM; ++j) acc += cj[j] * We[o * TDIM + j];
        table[(size_t)k * DH + o] = acc;
    }
}

// ---------------------------------------------------------------------------
// bcount: coarse-bucket histogram (LDS-aggregated)
// ---------------------------------------------------------------------------
__global__ __launch_bounds__(256) void bcount_k(
    const int* __restrict__ ei, int* __restrict__ bcnt, int E, int NBK)
{
    __shared__ int lc[NBKMAX];
    for (int i = threadIdx.x; i < NBKMAX; i += 256) lc[i] = 0;
    __syncthreads();
    int base = blockIdx.x * TILE;
#pragma unroll 4
    for (int i = 0; i < TILE / 256; ++i) {
        int e = base + i * 256 + threadIdx.x;
        if (e < E) atomicAdd(&lc[((unsigned int)ei[E + e]) >> NBSH], 1);
    }
    __syncthreads();
    for (int b = threadIdx.x; b < NBK; b += 256) {
        int c = lc[b];
        if (c) atomicAdd(&bcnt[b], c);
    }
}

// ---------------------------------------------------------------------------
// bscan: single block; exclusive scan of bcnt -> bstart, init bcur, off[N]=E
// ---------------------------------------------------------------------------
__global__ __launch_bounds__(512) void bscan_k(
    const int* __restrict__ bcnt, int* __restrict__ bstart,
    int* __restrict__ bcur, int* __restrict__ off, int N, int E, int NBK)
{
    __shared__ int sd[512];
    int t = threadIdx.x;
    int v0 = (t < NBK) ? bcnt[t] : 0;
    sd[t] = v0;
    __syncthreads();
    for (int st = 1; st < 512; st <<= 1) {
        int v = (t >= st) ? sd[t - st] : 0;
        __syncthreads();
        sd[t] += v;
        __syncthreads();
    }
    int ex = sd[t] - v0;
    if (t < NBK) { bstart[t] = ex; bcur[t] = ex; }
    if (t == 0)  { bstart[NBK] = E; off[N] = E; }
}

// ---------------------------------------------------------------------------
// S1: LDS-sorted tile scatter. Tile is bucket-sorted in LDS, then written out
//     coalesced. stg entry = {src | localdst<<17, tabidx}
// ---------------------------------------------------------------------------
__global__ __launch_bounds__(512) void s1_bucket(
    const int* __restrict__ ei, const float* __restrict__ t,
    const float* __restrict__ ntime,
    int* __restrict__ bcur, int2* __restrict__ stg, int E, int NBK)
{
    __shared__ int2 tile[TILE];       // 64 KB
    __shared__ int  lcnt[NBKMAX];     // counts -> scan temp
    __shared__ int  lcur[NBKMAX];     // scatter cursor (starts at lofs)
    __shared__ int  gdel[NBKMAX];     // gpos[b] - lofs[b]

    int tid = threadIdx.x;
    int base = blockIdx.x * TILE;
    int cnt_here = min(TILE, E - base);

    for (int i = tid; i < NBKMAX; i += 512) lcnt[i] = 0;
    __syncthreads();

    // phase A: per-bucket counts for this tile
#pragma unroll 4
    for (int i = 0; i < TILE / 512; ++i) {
        int e = base + i * 512 + tid;
        if (e < E) atomicAdd(&lcnt[((unsigned int)ei[E + e]) >> NBSH], 1);
    }
    __syncthreads();

    // block-wide exclusive scan of lcnt -> lofs (in lcur), reserve global runs
    {
        int v0 = (tid < NBK) ? lcnt[tid] : 0;
        // Hillis-Steele inclusive on a 512 temp (reuse gdel as temp is unsafe;
        // use a register ladder over lcnt directly with barriers)
        __shared__ int sd[512];
        sd[tid] = v0;
        __syncthreads();
        for (int st = 1; st < 512; st <<= 1) {
            int v = (tid >= st) ? sd[tid - st] : 0;
            __syncthreads();
            sd[tid] += v;
            __syncthreads();
        }
        int lofs = sd[tid] - v0;   // exclusive
        if (tid < NBK) {
            int gpos = (v0 > 0) ? atomicAdd(&bcur[tid], v0) : 0;
            lcur[tid] = lofs;
            gdel[tid] = gpos - lofs;
        }
    }
    __syncthreads();

    // phase B: park entries in LDS at bucket-sorted ranks
#pragma unroll 4
    for (int i = 0; i < TILE / 512; ++i) {
        int e = base + i * 512 + tid;
        if (e < E) {
            int d = ei[E + e];
            int s = ei[e];
            float rel = ntime[s] - t[e];
            float u = fmaf(rel, (float)(TABK / 2), (float)(TABK / 2) + 0.5f);
            int idx = (int)u;
            idx = min(max(idx, 0), TABK - 1);
            int b = ((unsigned int)d) >> NBSH;
            int r = atomicAdd(&lcur[b], 1);
            tile[r] = make_int2(s | ((d & ((1 << NBSH) - 1)) << 17),
                                idx | (b << 20));
        }
    }
    __syncthreads();

    // phase C: coalesced write-out. consecutive k within a run -> consecutive
    // global addresses.
    for (int k = tid; k < cnt_here; k += 512) {
        int2 en = tile[k];
        int b = ((unsigned int)en.y) >> 20;
        stg[gdel[b] + k] = make_int2(en.x, en.y & 0xFFFFF);
    }
}

// ---------------------------------------------------------------------------
// S2: per-bucket LDS histogram + scan -> off[]; scatter 4B payload
//     payload = src | tabidx<<17
// ---------------------------------------------------------------------------
__global__ __launch_bounds__(256) void s2_hist_scatter(
    const int* __restrict__ bstart, const int2* __restrict__ stg,
    int* __restrict__ payload, int* __restrict__ off, int N)
{
    __shared__ int lcnt[1 << NBSH];
    int t = threadIdx.x;
    int nb0 = blockIdx.x << NBSH;
    lcnt[t] = 0;
    __syncthreads();

    int lo = bstart[blockIdx.x];
    int hi = bstart[blockIdx.x + 1];

    // pass 1: local histogram
    for (int i = lo + t; i < hi; i += 256)
        atomicAdd(&lcnt[((unsigned int)stg[i].x) >> 17], 1);
    __syncthreads();

    // in-place Hillis-Steele inclusive scan (256 wide)
    int cntv = lcnt[t];
    for (int st = 1; st < 256; st <<= 1) {
        int v = (t >= st) ? lcnt[t - st] : 0;
        __syncthreads();
        lcnt[t] += v;
        __syncthreads();
    }
    int gpos = lo + lcnt[t] - cntv;   // global CSR offset for node nb0+t
    if (nb0 + t < N) off[nb0 + t] = gpos;
    __syncthreads();
    lcnt[t] = gpos;                    // becomes the scatter cursor
    __syncthreads();

    // pass 2: scatter to final position (stg run is L2-hot)
    for (int i = lo + t; i < hi; i += 256) {
        int2 pl = stg[i];
        int ld = ((unsigned int)pl.x) >> 17;
        int pos = atomicAdd(&lcnt[ld], 1);
        payload[pos] = (pl.x & 0x1FFFF) | (pl.y << 17);
    }
}

// ---------------------------------------------------------------------------
// gather + finalize. 32 lanes per dst (4 edges in flight), no atomics.
// ---------------------------------------------------------------------------
__global__ __launch_bounds__(256) void gather_pass(
    const int* __restrict__ off, const int* __restrict__ payload,
    const float* __restrict__ qn, const unsigned short* __restrict__ kvn,
    const float* __restrict__ skv, const float* __restrict__ table,
    const float* __restrict__ Wout, const float* __restrict__ bout,
    float* __restrict__ out, int N)
{
    int tid = blockIdx.x * blockDim.x + threadIdx.x;
    int d    = tid >> 5;         // 32 lanes per dst
    int quar = (tid >> 3) & 3;   // edge slot 0..3
    int sub  = tid & 7;          // channel group: 4 floats each
    if (d >= N) return;

    const float4 q = *(const float4*)(qn + (size_t)d * DH + sub * 4);
    float4 acc; acc.x = acc.y = acc.z = acc.w = 0.0f;
    float ssum = 0.0f;

    int beg = off[d];
    int end = off[d + 1];
    int j = beg + quar;
    int p = (j < end) ? payload[j] : 0;
    for (; j < end; j += 4) {
        int pc = p;
        if (j + 4 < end) p = payload[j + 4];   // prefetch next edge

        int src = pc & 0x1FFFF;
        int idx = ((unsigned int)pc) >> 17;

        const float4 ev = *(const float4*)(table + (size_t)idx * DH + sub * 4);
        const unsigned short* row = kvn + (size_t)src * 64;
        uint2 kb = *(const uint2*)(row + sub * 4);
        uint2 vb = *(const uint2*)(row + 32 + sub * 4);

        float part = q.x * (bfl(kb.x) + ev.x) + q.y * (bfh(kb.x) + ev.y)
                   + q.z * (bfl(kb.y) + ev.z) + q.w * (bfh(kb.y) + ev.w);
        part += __shfl_xor(part, 1);
        part += __shfl_xor(part, 2);
        float wgt = __expf(part * 0.25f);   // 1/sqrt(C)=0.25; logits tiny, no max needed
        ssum += wgt;

        acc.x += (bfl(vb.x) + ev.x) * wgt;
        acc.y += (bfh(vb.x) + ev.y) * wgt;
        acc.z += (bfl(vb.y) + ev.z) * wgt;
        acc.w += (bfh(vb.y) + ev.w) * wgt;
    }

    // combine the four edge slots
    acc.x += __shfl_xor(acc.x, 8);
    acc.y += __shfl_xor(acc.y, 8);
    acc.z += __shfl_xor(acc.z, 8);
    acc.w += __shfl_xor(acc.w, 8);
    ssum  += __shfl_xor(ssum, 8);
    acc.x += __shfl_xor(acc.x, 16);
    acc.y += __shfl_xor(acc.y, 16);
    acc.z += __shfl_xor(acc.z, 16);
    acc.w += __shfl_xor(acc.w, 16);
    ssum  += __shfl_xor(ssum, 16);

    float r = (ssum > 0.0f) ? 1.0f / ssum : 0.0f;
    const float4 sk = *(const float4*)(skv + (size_t)d * DH + sub * 4);
    float h0 = acc.x * r + sk.x;
    float h1 = acc.y * r + sk.y;
    float h2 = acc.z * r + sk.z;
    float h3 = acc.w * r + sk.w;

    const float4 w0 = *(const float4*)(Wout + sub * 4);
    const float4 w1 = *(const float4*)(Wout + DH + sub * 4);
    float l0 = h0 * w0.x + h1 * w0.y + h2 * w0.z + h3 * w0.w;
    float l1 = h0 * w1.x + h1 * w1.y + h2 * w1.z + h3 * w1.w;
    l0 += __shfl_xor(l0, 1); l0 += __shfl_xor(l0, 2); l0 += __shfl_xor(l0, 4);
    l1 += __shfl_xor(l1, 1); l1 += __shfl_xor(l1, 2); l1 += __shfl_xor(l1, 4);

    if ((tid & 31) == 0) {
        l0 += bout[0];
        l1 += bout[1];
        float m = fmaxf(l0, l1);
        float lse = m + logf(__expf(l0 - m) + __expf(l1 - m));
        float2 o; o.x = l0 - lse; o.y = l1 - lse;
        *(float2*)(out + (size_t)d * 2) = o;
    }
}

// ---------------------------------------------------------------------------
extern "C" void kernel_launch(void* const* d_in, const int* in_sizes, int n_in,
                              void* d_out, int out_size, void* d_ws, size_t ws_size,
                              hipStream_t stream)
{
    const float* x      = (const float*)d_in[0];
    const int*   ei     = (const int*)d_in[1];
    const float* t      = (const float*)d_in[2];
    const float* ntime  = (const float*)d_in[3];
    const float* freq   = (const float*)d_in[4];
    const float* phase  = (const float*)d_in[5];
    const float* Wl     = (const float*)d_in[6];
    const float* bl     = (const float*)d_in[7];
    const float* Wq     = (const float*)d_in[8];
    const float* bq     = (const float*)d_in[9];
    const float* Wk     = (const float*)d_in[10];
    const float* bk     = (const float*)d_in[11];
    const float* Wv     = (const float*)d_in[12];
    const float* bv     = (const float*)d_in[13];
    const float* We     = (const float*)d_in[14];
    const float* be     = (const float*)d_in[15];
    const float* Ws     = (const float*)d_in[16];
    const float* bs     = (const float*)d_in[17];
    const float* Wout   = (const float*)d_in[18];
    const float* bout   = (const float*)d_in[19];

    const int E = in_sizes[2];        // t has E elements
    const int N = in_sizes[3];        // node_time has N elements
    const int NBK = (N + (1 << NBSH) - 1) >> NBSH;   // buckets of 256 nodes

    char* wsb = (char*)d_ws;
    int2*  stg     = (int2*)wsb;            wsb += (size_t)E * sizeof(int2);
    int*   payload = (int*)wsb;             wsb += (size_t)E * sizeof(int);
    float* qn   = (float*)wsb;              wsb += (size_t)N * DH * 4;
    unsigned short* kvn = (unsigned short*)wsb; wsb += (size_t)N * 64 * 2;
    float* skv  = (float*)wsb;              wsb += (size_t)N * DH * 4;
    float* tab  = (float*)wsb;              wsb += (size_t)(TABK + 1) * DH * 4;
    int*   off  = (int*)wsb;                wsb += (size_t)(N + 1) * 4;
    int*   bcnt = (int*)wsb;                wsb += NBKMAX * 4;
    int*   bstart = (int*)wsb;              wsb += (NBKMAX + 1) * 4;
    int*   bcur = (int*)wsb;                wsb += NBKMAX * 4;

    float* out = (float*)d_out;

    int nblk = (N + 255) / 256;
    int tblk = (E + TILE - 1) / TILE;

    node_prep<<<nblk, 256, 0, stream>>>(x, Wl, bl, Wq, bq, Wk, bk, Wv, bv, Ws, bs,
                                        qn, kvn, skv, bcnt, N);
    build_table<<<(TABK + 64) / 64, 64, 0, stream>>>(We, be, freq, phase, tab);
    bcount_k<<<tblk, 256, 0, stream>>>(ei, bcnt, E, NBK);
    bscan_k<<<1, 512, 0, stream>>>(bcnt, bstart, bcur, off, N, E, NBK);
    s1_bucket<<<tblk, 512, 0, stream>>>(ei, t, ntime, bcur, stg, E, NBK);
    s2_hist_scatter<<<NBK, 256, 0, stream>>>(bstart, stg, payload, off, N);

    int gblk = ((size_t)N * 32 + 255) / 256;
    gather_pass<<<gblk, 256, 0, stream>>>(off, payload, qn, kvn, skv,
                                          tab, Wout, bout, out, N);
}